// Round 7
// baseline (3744.337 us; speedup 1.0000x reference)
//
#include <hip/hip_runtime.h>
#include <hip/hip_bf16.h>

// INT8 dynamic-quant GEMM: out = (x_int8 @ w_int8^T) * (x_scales * w_scales^T)
// x: [M,K] f32, w: [N,K] f32, out: [M,N] f32.  M=8192, K=4096, N=11008.

#define QEPS 1e-5f

using int4v = __attribute__((ext_vector_type(4))) int;

typedef __attribute__((address_space(3))) signed char lds_i8_t;
typedef __attribute__((address_space(1))) const signed char glb_i8_t;

// ---------------- per-row absmax quantize (K = 4096 fixed) ----------------
__global__ __launch_bounds__(256) void quant_rows_k(const float* __restrict__ in,
                                                    signed char* __restrict__ out8,
                                                    float* __restrict__ scales) {
    const int K = 4096;
    const int row = blockIdx.x;
    const int t = threadIdx.x;
    const float4* in4 = (const float4*)(in + (size_t)row * K);
    float4 v[4];
    float amax = 0.f;
#pragma unroll
    for (int j = 0; j < 4; ++j) {
        v[j] = in4[t + 256 * j];
        amax = fmaxf(amax, fmaxf(fmaxf(fabsf(v[j].x), fabsf(v[j].y)),
                                 fmaxf(fabsf(v[j].z), fabsf(v[j].w))));
    }
#pragma unroll
    for (int off = 32; off > 0; off >>= 1)
        amax = fmaxf(amax, __shfl_xor(amax, off));
    __shared__ float wmax[4];
    if ((t & 63) == 0) wmax[t >> 6] = amax;
    __syncthreads();
    amax = fmaxf(fmaxf(wmax[0], wmax[1]), fmaxf(wmax[2], wmax[3]));
    const float scale = fmaxf(amax, QEPS) / 127.0f;
    if (t == 0) scales[row] = scale;
    char4* o4 = (char4*)(out8 + (size_t)row * K);
#pragma unroll
    for (int j = 0; j < 4; ++j) {
        char4 q;
        q.x = (signed char)(int)rintf(v[j].x / scale);  // rintf = round-half-even = jnp.round
        q.y = (signed char)(int)rintf(v[j].y / scale);
        q.z = (signed char)(int)rintf(v[j].z / scale);
        q.w = (signed char)(int)rintf(v[j].w / scale);
        o4[t + 256 * j] = q;
    }
}

// ---- int8 GEMM, 256x256 tile, BK=64, double-buffer (64 KB -> 2 blocks/CU) ----
// The round-2 (measured-best) 2-phase counted-vmcnt schedule, with LDS halved so
// TWO blocks fit per CU: one block's stage/LDS phase overlaps the other block's
// MFMA phase (cross-block wave overlap -- the structural fix for the measured
// LDS+MFMA serialization at 1 block/CU).
// LDS rows are 64 B, XOR swizzle lds[row][c]=global[row][c ^ ((row>>1)&3)<<4]
// (verified 0 conflicts in round 5); staging via pre-swizzled global source,
// linear LDS dest (required by global_load_lds).
// Per K-step: compute(buf); barrier; STAGE(buf, u+2); vmcnt(4) <- waits tile
// u+1 issued LAST iteration (full-iteration lead, never drains to 0); barrier.
__global__ __launch_bounds__(512, 4) void gemm_i8_db(const signed char* __restrict__ A,
                                                     const signed char* __restrict__ B,
                                                     const float* __restrict__ xs,
                                                     const float* __restrict__ wsc,
                                                     float* __restrict__ C) {
    constexpr int K = 4096;
    constexpr int N = 11008;
    constexpr int BK = 64;
    constexpr int NT = K / BK;        // 64
    constexpr int TILE = 256 * BK;    // 16 KB per matrix per buffer

    __shared__ __align__(16) signed char lsA[2][TILE];  // 32 KB
    __shared__ __align__(16) signed char lsB[2][TILE];  // 32 KB

    const int t = threadIdx.x;
    const int lane = t & 63;
    const int wid = t >> 6;
    const int wr = wid >> 2;   // 0..1 -> 128 output rows
    const int wc = wid & 3;    // 0..3 -> 64 output cols

    // XCD-aware swizzle: grid 1376 = 8 XCDs x 172 (bijective)
    const int wg = (blockIdx.x & 7) * ((int)gridDim.x >> 3) + ((int)blockIdx.x >> 3);
    const int by = wg / 43;
    const int bx = wg - by * 43;
    const int brow = by * 256;
    const int bcol = bx * 256;

    // staging: chunk = i*512 + t (i=0,1); row = chunk>>2, slot = chunk&3
    const int srow = t >> 2;                                    // 0..127 (+128 for i=1)
    const int scol = ((t & 3) * 16) ^ (((t >> 3) & 3) << 4);    // slot*16 ^ ((row>>1)&3)<<4
    const signed char* aSrc = A + (size_t)(brow + srow) * K + scol;
    const signed char* bSrc = B + (size_t)(bcol + srow) * K + scol;

    // fragment geometry (mfma_i32_16x16x64_i8): row = lane&15, k-grp = (lane>>4)*16
    const int arow0 = wr * 128 + (lane & 15);
    const int bcol0 = wc * 64 + (lane & 15);
    const int colf = ((lane >> 4) * 16) ^ ((((lane & 15) >> 1) & 3) << 4);

    int4v acc[8][4];
#pragma unroll
    for (int m = 0; m < 8; ++m)
#pragma unroll
        for (int n = 0; n < 4; ++n) acc[m][n] = (int4v){0, 0, 0, 0};

#define STAGE(BUF, KT)                                                                     \
    do {                                                                                   \
        const size_t ko = (size_t)(KT)*BK;                                                 \
        __builtin_amdgcn_global_load_lds((glb_i8_t*)(aSrc + ko),                           \
                                         (lds_i8_t*)(&lsA[BUF][0] + t * 16), 16, 0, 0);    \
        __builtin_amdgcn_global_load_lds((glb_i8_t*)(aSrc + (size_t)128 * K + ko),         \
                                         (lds_i8_t*)(&lsA[BUF][8192] + t * 16), 16, 0, 0); \
        __builtin_amdgcn_global_load_lds((glb_i8_t*)(bSrc + ko),                           \
                                         (lds_i8_t*)(&lsB[BUF][0] + t * 16), 16, 0, 0);    \
        __builtin_amdgcn_global_load_lds((glb_i8_t*)(bSrc + (size_t)128 * K + ko),         \
                                         (lds_i8_t*)(&lsB[BUF][8192] + t * 16), 16, 0, 0); \
    } while (0)

    auto compute_tile = [&](const signed char* LA, const signed char* LB) {
        int4v bf[4];
#pragma unroll
        for (int n = 0; n < 4; ++n)
            bf[n] = *(const int4v*)(LB + (bcol0 + n * 16) * 64 + colf);
        int4v af[8];
#pragma unroll
        for (int mi = 0; mi < 8; ++mi)
            af[mi] = *(const int4v*)(LA + (arow0 + mi * 16) * 64 + colf);
        __builtin_amdgcn_s_setprio(1);
#pragma unroll
        for (int mi = 0; mi < 8; ++mi)
#pragma unroll
            for (int n = 0; n < 4; ++n)
                acc[mi][n] = __builtin_amdgcn_mfma_i32_16x16x64_i8(af[mi], bf[n],
                                                                   acc[mi][n], 0, 0, 0);
        __builtin_amdgcn_s_setprio(0);
    };

    // prologue: stage tiles 0,1 into bufs 0,1; wait for tile 0 only
    STAGE(0, 0);
    STAGE(1, 1);
    asm volatile("s_waitcnt vmcnt(4)" ::: "memory");
    __builtin_amdgcn_s_barrier();

#pragma unroll 1
    for (int u = 0; u < NT; ++u) {
        const int buf = u & 1;
        compute_tile(&lsA[buf][0], &lsB[buf][0]);
        __builtin_amdgcn_s_barrier();                     // all waves done reading buf
        STAGE(buf, (u + 2) & (NT - 1));                   // wrapped tail: redundant-but-safe
        asm volatile("s_waitcnt vmcnt(4)" ::: "memory");  // tile u+1 landed; u+2 in flight
        __builtin_amdgcn_s_barrier();
    }
#undef STAGE

    // drain staged loads before workgroup teardown
    asm volatile("s_waitcnt vmcnt(0)" ::: "memory");

    // epilogue: C/D frag layout col=lane&15, row=(lane>>4)*4+reg
    const int rgrp = (lane >> 4) * 4;
    float wsv[4];
#pragma unroll
    for (int n = 0; n < 4; ++n) wsv[n] = wsc[bcol + wc * 64 + n * 16 + (lane & 15)];
#pragma unroll
    for (int m = 0; m < 8; ++m) {
#pragma unroll
        for (int r = 0; r < 4; ++r) {
            const int row = brow + wr * 128 + m * 16 + rgrp + r;
            const float xsv = xs[row];
            const size_t base = (size_t)row * N + bcol + wc * 64 + (lane & 15);
#pragma unroll
            for (int n = 0; n < 4; ++n)
                C[base + n * 16] = (float)acc[m][n][r] * (xsv * wsv[n]);
        }
    }
}

extern "C" void kernel_launch(void* const* d_in, const int* in_sizes, int n_in,
                              void* d_out, int out_size, void* d_ws, size_t ws_size,
                              hipStream_t stream) {
    const float* x = (const float*)d_in[0];
    const float* w = (const float*)d_in[1];
    float* out = (float*)d_out;

    const int K = 4096;
    const int M = in_sizes[0] / K;   // 8192
    const int N = in_sizes[1] / K;   // 11008

    signed char* x8 = (signed char*)d_ws;
    signed char* w8 = x8 + (size_t)M * K;
    float* xscales = (float*)(w8 + (size_t)N * K);
    float* wscales = xscales + M;

    quant_rows_k<<<M, 256, 0, stream>>>(x, x8, xscales);
    quant_rows_k<<<N, 256, 0, stream>>>(w, w8, wscales);
    const int nwg = (M / 256) * (N / 256);   // 32*43 = 1376 = 8*172
    gemm_i8_db<<<nwg, 512, 0, stream>>>(x8, w8, xscales, wscales, out);
}

// Round 8
// 630.891 us; speedup vs baseline: 5.9350x; 5.9350x over previous
//
#include <hip/hip_runtime.h>
#include <hip/hip_bf16.h>

// INT8 dynamic-quant GEMM: out = (x_int8 @ w_int8^T) * (x_scales * w_scales^T)
// x: [M,K] f32, w: [N,K] f32, out: [M,N] f32.  M=8192, K=4096, N=11008.

#define QEPS 1e-5f

using int4v = __attribute__((ext_vector_type(4))) int;

typedef __attribute__((address_space(3))) signed char lds_i8_t;
typedef __attribute__((address_space(1))) const signed char glb_i8_t;

// ---------------- per-row absmax quantize (K = 4096 fixed) ----------------
__global__ __launch_bounds__(256) void quant_rows_k(const float* __restrict__ in,
                                                    signed char* __restrict__ out8,
                                                    float* __restrict__ scales) {
    const int K = 4096;
    const int row = blockIdx.x;
    const int t = threadIdx.x;
    const float4* in4 = (const float4*)(in + (size_t)row * K);
    float4 v[4];
    float amax = 0.f;
#pragma unroll
    for (int j = 0; j < 4; ++j) {
        v[j] = in4[t + 256 * j];
        amax = fmaxf(amax, fmaxf(fmaxf(fabsf(v[j].x), fabsf(v[j].y)),
                                 fmaxf(fabsf(v[j].z), fabsf(v[j].w))));
    }
#pragma unroll
    for (int off = 32; off > 0; off >>= 1)
        amax = fmaxf(amax, __shfl_xor(amax, off));
    __shared__ float wmax[4];
    if ((t & 63) == 0) wmax[t >> 6] = amax;
    __syncthreads();
    amax = fmaxf(fmaxf(wmax[0], wmax[1]), fmaxf(wmax[2], wmax[3]));
    const float scale = fmaxf(amax, QEPS) / 127.0f;
    if (t == 0) scales[row] = scale;
    char4* o4 = (char4*)(out8 + (size_t)row * K);
#pragma unroll
    for (int j = 0; j < 4; ++j) {
        char4 q;
        q.x = (signed char)(int)rintf(v[j].x / scale);  // rintf = round-half-even = jnp.round
        q.y = (signed char)(int)rintf(v[j].y / scale);
        q.z = (signed char)(int)rintf(v[j].z / scale);
        q.w = (signed char)(int)rintf(v[j].w / scale);
        o4[t + 256 * j] = q;
    }
}

// ---- int8 GEMM, 128x128 tile, 256 thr / 4 waves, BK=128 dbuf, 2 blocks/CU ----
// Rationale: 256^2/1-block schedules all plateau at MfmaUtil ~38% (R2/R6) --
// barrier-locked waves serialize LDS bursts vs MFMA. 128^2 with 64 KB LDS and
// ~135 VGPR gives TWO independent blocks per CU: each SIMD runs 2 waves from
// different blocks, so one block's stage/barrier/lgkmcnt phase is covered by
// the other's MFMA burst. NO launch_bounds min-wave forcing (R7 lesson: acc
// cannot be squeezed; forcing caps => catastrophic spills).
// Staging/swizzle/fragments are R1/R2's verified pattern (0 bank conflicts):
// rows of 128 B, lds[row][c]=global[row][c ^ ((row&7)<<4)] via pre-swizzled
// global source, linear LDS dest. Schedule is R2's counted-vmcnt double
// buffer: compute(buf); barrier; STAGE(buf,u+2); vmcnt(8); barrier.
// Grid order: by = wg&63, bx = wg>>6  =>  xcd = blockIdx%8 = by%8, so each
// XCD keeps its 8 A-panels (4 MB = its L2) resident; B panels flow via L3.
__global__ __launch_bounds__(256) void gemm_i8_128(const signed char* __restrict__ A,
                                                   const signed char* __restrict__ B,
                                                   const float* __restrict__ xs,
                                                   const float* __restrict__ wsc,
                                                   float* __restrict__ C) {
    constexpr int K = 4096;
    constexpr int N = 11008;
    constexpr int BK = 128;
    constexpr int NT = K / BK;        // 32
    constexpr int TILE = 128 * 128;   // 16 KB per matrix per buffer

    __shared__ __align__(16) signed char lsA[2][TILE];  // 32 KB
    __shared__ __align__(16) signed char lsB[2][TILE];  // 32 KB

    const int t = threadIdx.x;
    const int lane = t & 63;
    const int wid = t >> 6;
    const int wr = wid >> 1;   // 0..1 -> 64 output rows
    const int wc = wid & 1;    // 0..1 -> 64 output cols

    // column-major grid order: 64 row-blocks fixed inner => xcd = by%8 (see header)
    const int wg = blockIdx.x;
    const int by = wg & 63;
    const int bx = wg >> 6;
    const int brow = by * 128;
    const int bcol = bx * 128;

    // staging: per call, row = j*32 + (t>>3), slot = t&7 (8 lanes x 16 B = 128 B rows)
    const int srow = t >> 3;                                  // 0..31
    const int scol = ((t & 7) * 16) ^ ((srow & 7) << 4);      // pre-swizzled source col
    const signed char* aSrc = A + (size_t)(brow + srow) * K + scol;
    const signed char* bSrc = B + (size_t)(bcol + srow) * K + scol;

    // fragment geometry (mfma_i32_16x16x64_i8): row = lane&15, k-grp = (lane>>4)*16
    const int arow0 = wr * 64 + (lane & 15);
    const int bcol0 = wc * 64 + (lane & 15);
    const int kgrp = (lane >> 4) * 16;
    const int sw = (lane & 7) << 4;   // row&7 == lane&7 for all fragment rows

    int4v acc[4][4];
#pragma unroll
    for (int m = 0; m < 4; ++m)
#pragma unroll
        for (int n = 0; n < 4; ++n) acc[m][n] = (int4v){0, 0, 0, 0};

#define STAGE(BUF, KT)                                                                      \
    do {                                                                                    \
        const size_t ko = (size_t)(KT)*BK;                                                  \
        _Pragma("unroll") for (int j = 0; j < 4; ++j)                                       \
            __builtin_amdgcn_global_load_lds(                                               \
                (glb_i8_t*)(aSrc + (size_t)(j * 32) * K + ko),                              \
                (lds_i8_t*)(&lsA[BUF][0] + (j * 256 + t) * 16), 16, 0, 0);                  \
        _Pragma("unroll") for (int j = 0; j < 4; ++j)                                       \
            __builtin_amdgcn_global_load_lds(                                               \
                (glb_i8_t*)(bSrc + (size_t)(j * 32) * K + ko),                              \
                (lds_i8_t*)(&lsB[BUF][0] + (j * 256 + t) * 16), 16, 0, 0);                  \
    } while (0)

    auto compute_tile = [&](const signed char* LA, const signed char* LB) {
#pragma unroll
        for (int ks = 0; ks < 2; ++ks) {
            const int col = (ks * 64 + kgrp) ^ sw;
            int4v bf[4], af[4];
#pragma unroll
            for (int n = 0; n < 4; ++n)
                bf[n] = *(const int4v*)(LB + (bcol0 + n * 16) * 128 + col);
#pragma unroll
            for (int mi = 0; mi < 4; ++mi)
                af[mi] = *(const int4v*)(LA + (arow0 + mi * 16) * 128 + col);
            __builtin_amdgcn_s_setprio(1);
#pragma unroll
            for (int mi = 0; mi < 4; ++mi)
#pragma unroll
                for (int n = 0; n < 4; ++n)
                    acc[mi][n] = __builtin_amdgcn_mfma_i32_16x16x64_i8(af[mi], bf[n],
                                                                       acc[mi][n], 0, 0, 0);
            __builtin_amdgcn_s_setprio(0);
        }
    };

    // prologue: stage tiles 0,1; wait for tile 0 only (tile 1 stays in flight)
    STAGE(0, 0);
    STAGE(1, 1);
    asm volatile("s_waitcnt vmcnt(8)" ::: "memory");
    __builtin_amdgcn_s_barrier();

#pragma unroll 1
    for (int u = 0; u < NT; ++u) {
        const int buf = u & 1;
        compute_tile(&lsA[buf][0], &lsB[buf][0]);
        __builtin_amdgcn_s_barrier();                     // all waves done reading buf
        STAGE(buf, (u + 2) & (NT - 1));                   // wrapped tail: redundant-but-safe
        asm volatile("s_waitcnt vmcnt(8)" ::: "memory");  // tile u+1 landed; u+2 in flight
        __builtin_amdgcn_s_barrier();
    }
#undef STAGE

    // drain staged loads before workgroup teardown
    asm volatile("s_waitcnt vmcnt(0)" ::: "memory");

    // epilogue: C/D frag layout col=lane&15, row=(lane>>4)*4+reg
    const int rgrp = (lane >> 4) * 4;
    float wsv[4];
#pragma unroll
    for (int n = 0; n < 4; ++n) wsv[n] = wsc[bcol + wc * 64 + n * 16 + (lane & 15)];
#pragma unroll
    for (int m = 0; m < 4; ++m) {
#pragma unroll
        for (int r = 0; r < 4; ++r) {
            const int row = brow + wr * 64 + m * 16 + rgrp + r;
            const float xsv = xs[row];
            const size_t base = (size_t)row * N + bcol + wc * 64 + (lane & 15);
#pragma unroll
            for (int n = 0; n < 4; ++n)
                C[base + n * 16] = (float)acc[m][n][r] * (xsv * wsv[n]);
        }
    }
}

extern "C" void kernel_launch(void* const* d_in, const int* in_sizes, int n_in,
                              void* d_out, int out_size, void* d_ws, size_t ws_size,
                              hipStream_t stream) {
    const float* x = (const float*)d_in[0];
    const float* w = (const float*)d_in[1];
    float* out = (float*)d_out;

    const int K = 4096;
    const int M = in_sizes[0] / K;   // 8192
    const int N = in_sizes[1] / K;   // 11008

    signed char* x8 = (signed char*)d_ws;
    signed char* w8 = x8 + (size_t)M * K;
    float* xscales = (float*)(w8 + (size_t)N * K);
    float* wscales = xscales + M;

    quant_rows_k<<<M, 256, 0, stream>>>(x, x8, xscales);
    quant_rows_k<<<N, 256, 0, stream>>>(w, w8, wscales);
    const int nwg = (M / 128) * (N / 128);   // 64 * 86 = 5504
    gemm_i8_128<<<nwg, 256, 0, stream>>>(x8, w8, xscales, wscales, out);
}

// Round 9
// 509.471 us; speedup vs baseline: 7.3495x; 1.2383x over previous
//
#include <hip/hip_runtime.h>
#include <hip/hip_bf16.h>

// INT8 dynamic-quant GEMM: out = (x_int8 @ w_int8^T) * (x_scales * w_scales^T)
// x: [M,K] f32, w: [N,K] f32, out: [M,N] f32.  M=8192, K=4096, N=11008.

#define QEPS 1e-5f

using int4v = __attribute__((ext_vector_type(4))) int;
using int16v = __attribute__((ext_vector_type(16))) int;
using f32x4 = __attribute__((ext_vector_type(4))) float;

typedef __attribute__((address_space(3))) signed char lds_i8_t;
typedef __attribute__((address_space(1))) const signed char glb_i8_t;

// ---------------- per-row absmax quantize (K = 4096 fixed) ----------------
__global__ __launch_bounds__(256) void quant_rows_k(const float* __restrict__ in,
                                                    signed char* __restrict__ out8,
                                                    float* __restrict__ scales) {
    const int K = 4096;
    const int row = blockIdx.x;
    const int t = threadIdx.x;
    const float4* in4 = (const float4*)(in + (size_t)row * K);
    float4 v[4];
    float amax = 0.f;
#pragma unroll
    for (int j = 0; j < 4; ++j) {
        v[j] = in4[t + 256 * j];
        amax = fmaxf(amax, fmaxf(fmaxf(fabsf(v[j].x), fabsf(v[j].y)),
                                 fmaxf(fabsf(v[j].z), fabsf(v[j].w))));
    }
#pragma unroll
    for (int off = 32; off > 0; off >>= 1)
        amax = fmaxf(amax, __shfl_xor(amax, off));
    __shared__ float wmax[4];
    if ((t & 63) == 0) wmax[t >> 6] = amax;
    __syncthreads();
    amax = fmaxf(fmaxf(wmax[0], wmax[1]), fmaxf(wmax[2], wmax[3]));
    const float scale = fmaxf(amax, QEPS) / 127.0f;
    if (t == 0) scales[row] = scale;
    char4* o4 = (char4*)(out8 + (size_t)row * K);
#pragma unroll
    for (int j = 0; j < 4; ++j) {
        char4 q;
        q.x = (signed char)(int)rintf(v[j].x / scale);  // rintf = round-half-even = jnp.round
        q.y = (signed char)(int)rintf(v[j].y / scale);
        q.z = (signed char)(int)rintf(v[j].z / scale);
        q.w = (signed char)(int)rintf(v[j].w / scale);
        o4[t + 256 * j] = q;
    }
}

// ---- int8 GEMM, 256x256 tile, 32x32x32 MFMA, register-pipelined k-steps ----
// R2's verified staging/swizzle/double-buffer + counted vmcnt(8), upgraded:
// K-tile(128) = 4 k-steps of 32; two register fragment sets (even/odd). Each
// k-step: issue the NEXT step's 6 ds_read_b128 into the alternate set, then
// run 8 MFMAs of the current set -> ds_read latency/LDS contention hides
// under the MFMA burst instead of serializing (the measured ~2260 cyc/tile
// loss in R2). mfma_i32_32x32x32_i8: half the MFMA instructions, 4404 TOPS
// ceiling, and 24-VGPR frag sets (acc 128 + 2x24 + misc ~ 205 regs).
// Tile boundary: lgkmcnt(0); raw barrier; STAGE(u+2); vmcnt(8) (never 0);
// barrier -- staged loads stay in flight across barriers (T4).
__global__ __launch_bounds__(512, 2) void gemm_i8_pl(const signed char* __restrict__ A,
                                                     const signed char* __restrict__ B,
                                                     const float* __restrict__ xs,
                                                     const float* __restrict__ wsc,
                                                     float* __restrict__ C) {
    constexpr int K = 4096;
    constexpr int N = 11008;
    constexpr int BK = 128;
    constexpr int NT = 32;
    constexpr int TILE = 256 * 128;  // 32 KB

    __shared__ __align__(16) signed char lsA[2][TILE];
    __shared__ __align__(16) signed char lsB[2][TILE];

    const int t = threadIdx.x;
    const int lane = t & 63;
    const int wid = t >> 6;
    const int wr = wid >> 2;   // 0..1 -> 128 output rows
    const int wc = wid & 3;    // 0..3 -> 64 output cols

    // XCD-aware swizzle: grid 1376 = 8 XCDs x 172 (bijective)
    const int wg = (blockIdx.x & 7) * ((int)gridDim.x >> 3) + ((int)blockIdx.x >> 3);
    const int by = wg / 43;
    const int bx = wg - by * 43;
    const int brow = by * 256;
    const int bcol = bx * 256;

    // staging: row = t>>3 (+64 per j), slot = t&7; pre-swizzled source col
    const int srow = t >> 3;
    const int scol = ((t & 7) * 16) ^ ((srow & 7) << 4);
    const signed char* aSrc = A + (size_t)(brow + srow) * K + scol;
    const signed char* bSrc = B + (size_t)(bcol + srow) * K + scol;

    // fragment geometry (mfma_i32_32x32x32_i8): row = lane&31, k = (lane>>5)*16 + b
    const int r32 = lane & 31;
    const int khalf = (lane >> 5) * 16;
    const int sw = (lane & 7) << 4;         // LDS read XOR: (row&7)<<4, row&7 == lane&7
    const int aRow = wr * 128 + r32;        // + mi*32
    const int bRow = wc * 64 + r32;         // + n*32

    int16v acc[4][2];
#pragma unroll
    for (int m = 0; m < 4; ++m)
#pragma unroll
        for (int n = 0; n < 2; ++n)
#pragma unroll
            for (int r = 0; r < 16; ++r) acc[m][n][r] = 0;

    int4v af_e0, af_e1, af_e2, af_e3, bf_e0, bf_e1;
    int4v af_o0, af_o1, af_o2, af_o3, bf_o0, bf_o1;

#define SB __builtin_amdgcn_sched_barrier(0)

#define STAGE(BUF, KT)                                                                      \
    do {                                                                                    \
        const size_t ko = (size_t)(KT)*BK;                                                  \
        _Pragma("unroll") for (int j = 0; j < 4; ++j)                                       \
            __builtin_amdgcn_global_load_lds(                                               \
                (glb_i8_t*)(aSrc + (size_t)(j * 64) * K + ko),                              \
                (lds_i8_t*)(&lsA[BUF][0] + (j * 512 + t) * 16), 16, 0, 0);                  \
        _Pragma("unroll") for (int j = 0; j < 4; ++j)                                       \
            __builtin_amdgcn_global_load_lds(                                               \
                (glb_i8_t*)(bSrc + (size_t)(j * 64) * K + ko),                              \
                (lds_i8_t*)(&lsB[BUF][0] + (j * 512 + t) * 16), 16, 0, 0);                  \
    } while (0)

#define READS(P, BUF, S)                                                                    \
    do {                                                                                    \
        const signed char* LA = &lsA[BUF][0];                                               \
        const signed char* LB = &lsB[BUF][0];                                               \
        const int c = (((S)*32 + khalf)) ^ sw;                                              \
        af_##P##0 = *(const int4v*)(LA + (size_t)(aRow + 0) * 128 + c);                     \
        af_##P##1 = *(const int4v*)(LA + (size_t)(aRow + 32) * 128 + c);                    \
        af_##P##2 = *(const int4v*)(LA + (size_t)(aRow + 64) * 128 + c);                    \
        af_##P##3 = *(const int4v*)(LA + (size_t)(aRow + 96) * 128 + c);                    \
        bf_##P##0 = *(const int4v*)(LB + (size_t)(bRow + 0) * 128 + c);                     \
        bf_##P##1 = *(const int4v*)(LB + (size_t)(bRow + 32) * 128 + c);                    \
    } while (0)

#define MFMA8(P)                                                                            \
    do {                                                                                    \
        __builtin_amdgcn_s_setprio(1);                                                      \
        acc[0][0] = __builtin_amdgcn_mfma_i32_32x32x32_i8(af_##P##0, bf_##P##0, acc[0][0], 0, 0, 0); \
        acc[0][1] = __builtin_amdgcn_mfma_i32_32x32x32_i8(af_##P##0, bf_##P##1, acc[0][1], 0, 0, 0); \
        acc[1][0] = __builtin_amdgcn_mfma_i32_32x32x32_i8(af_##P##1, bf_##P##0, acc[1][0], 0, 0, 0); \
        acc[1][1] = __builtin_amdgcn_mfma_i32_32x32x32_i8(af_##P##1, bf_##P##1, acc[1][1], 0, 0, 0); \
        acc[2][0] = __builtin_amdgcn_mfma_i32_32x32x32_i8(af_##P##2, bf_##P##0, acc[2][0], 0, 0, 0); \
        acc[2][1] = __builtin_amdgcn_mfma_i32_32x32x32_i8(af_##P##2, bf_##P##1, acc[2][1], 0, 0, 0); \
        acc[3][0] = __builtin_amdgcn_mfma_i32_32x32x32_i8(af_##P##3, bf_##P##0, acc[3][0], 0, 0, 0); \
        acc[3][1] = __builtin_amdgcn_mfma_i32_32x32x32_i8(af_##P##3, bf_##P##1, acc[3][1], 0, 0, 0); \
        __builtin_amdgcn_s_setprio(0);                                                      \
    } while (0)

    // prologue: stage tiles 0,1; wait tile 0 only; prime even set with (tile0, s0)
    STAGE(0, 0);
    STAGE(1, 1);
    asm volatile("s_waitcnt vmcnt(8)" ::: "memory");
    __builtin_amdgcn_s_barrier();
    SB;
    READS(e, 0, 0);
    SB;

#pragma unroll 1
    for (int u = 0; u < NT; ++u) {
        const int buf = u & 1;
        const int nbuf = buf ^ 1;

        READS(o, buf, 1); SB;     // step 0: prefetch s1, MFMA s0
        MFMA8(e); SB;
        READS(e, buf, 2); SB;     // step 1: prefetch s2, MFMA s1
        MFMA8(o); SB;
        READS(o, buf, 3); SB;     // step 2: prefetch s3, MFMA s2
        MFMA8(e); SB;

        // tile boundary: this wave done reading buf; sync, stage u+2, gate u+1
        asm volatile("s_waitcnt lgkmcnt(0)" ::: "memory");
        SB;
        __builtin_amdgcn_s_barrier();
        STAGE(buf, (u + 2) & (NT - 1));                   // wrapped tail: redundant-but-safe
        asm volatile("s_waitcnt vmcnt(8)" ::: "memory");  // tile u+1 landed; u+2 in flight
        __builtin_amdgcn_s_barrier();
        SB;

        READS(e, nbuf, 0); SB;    // step 3: prefetch next tile s0, MFMA s3
        MFMA8(o); SB;
    }
#undef STAGE
#undef READS
#undef MFMA8

    // drain staged loads before workgroup teardown
    asm volatile("s_waitcnt vmcnt(0)" ::: "memory");

    // epilogue: 32x32 C/D layout: col = lane&31, row = (reg&3) + 8*(reg>>2) + 4*(lane>>5)
    const int lrow = (lane >> 5) * 4;
    const float wsv0 = wsc[bcol + wc * 64 + r32];
    const float wsv1 = wsc[bcol + wc * 64 + 32 + r32];
#pragma unroll
    for (int mi = 0; mi < 4; ++mi) {
        const int rbase = brow + wr * 128 + mi * 32 + lrow;
        f32x4 xq[4];
#pragma unroll
        for (int rq = 0; rq < 4; ++rq) xq[rq] = *(const f32x4*)&xs[rbase + 8 * rq];
#pragma unroll
        for (int rq = 0; rq < 4; ++rq)
#pragma unroll
            for (int rr = 0; rr < 4; ++rr) {
                const int row = rbase + 8 * rq + rr;
                const size_t base = (size_t)row * N + bcol + wc * 64 + r32;
                const float xv = xq[rq][rr];
                C[base] = (float)acc[mi][0][rq * 4 + rr] * (xv * wsv0);
                C[base + 32] = (float)acc[mi][1][rq * 4 + rr] * (xv * wsv1);
            }
    }
#undef SB
}

extern "C" void kernel_launch(void* const* d_in, const int* in_sizes, int n_in,
                              void* d_out, int out_size, void* d_ws, size_t ws_size,
                              hipStream_t stream) {
    const float* x = (const float*)d_in[0];
    const float* w = (const float*)d_in[1];
    float* out = (float*)d_out;

    const int K = 4096;
    const int M = in_sizes[0] / K;   // 8192
    const int N = in_sizes[1] / K;   // 11008

    signed char* x8 = (signed char*)d_ws;
    signed char* w8 = x8 + (size_t)M * K;
    float* xscales = (float*)(w8 + (size_t)N * K);
    float* wscales = xscales + M;

    quant_rows_k<<<M, 256, 0, stream>>>(x, x8, xscales);
    quant_rows_k<<<N, 256, 0, stream>>>(w, w8, wscales);
    const int nwg = (M / 256) * (N / 256);   // 32*43 = 1376 = 8*172
    gemm_i8_pl<<<nwg, 512, 0, stream>>>(x8, w8, xscales, wscales, out);
}

// Round 10
// 502.402 us; speedup vs baseline: 7.4529x; 1.0141x over previous
//
#include <hip/hip_runtime.h>
#include <hip/hip_bf16.h>

// INT8 dynamic-quant GEMM: out = (x_int8 @ w_int8^T) * (x_scales * w_scales^T)
// x: [M,K] f32, w: [N,K] f32, out: [M,N] f32.  M=8192, K=4096, N=11008.

#define QEPS 1e-5f

using int4v = __attribute__((ext_vector_type(4))) int;

typedef __attribute__((address_space(3))) signed char lds_i8_t;
typedef __attribute__((address_space(1))) const signed char glb_i8_t;

// ---------------- per-row absmax quantize (K = 4096 fixed) ----------------
__global__ __launch_bounds__(256) void quant_rows_k(const float* __restrict__ in,
                                                    signed char* __restrict__ out8,
                                                    float* __restrict__ scales) {
    const int K = 4096;
    const int row = blockIdx.x;
    const int t = threadIdx.x;
    const float4* in4 = (const float4*)(in + (size_t)row * K);
    float4 v[4];
    float amax = 0.f;
#pragma unroll
    for (int j = 0; j < 4; ++j) {
        v[j] = in4[t + 256 * j];
        amax = fmaxf(amax, fmaxf(fmaxf(fabsf(v[j].x), fabsf(v[j].y)),
                                 fmaxf(fabsf(v[j].z), fabsf(v[j].w))));
    }
#pragma unroll
    for (int off = 32; off > 0; off >>= 1)
        amax = fmaxf(amax, __shfl_xor(amax, off));
    __shared__ float wmax[4];
    if ((t & 63) == 0) wmax[t >> 6] = amax;
    __syncthreads();
    amax = fmaxf(fmaxf(wmax[0], wmax[1]), fmaxf(wmax[2], wmax[3]));
    const float scale = fmaxf(amax, QEPS) / 127.0f;
    if (t == 0) scales[row] = scale;
    char4* o4 = (char4*)(out8 + (size_t)row * K);
#pragma unroll
    for (int j = 0; j < 4; ++j) {
        char4 q;
        q.x = (signed char)(int)rintf(v[j].x / scale);  // rintf = round-half-even = jnp.round
        q.y = (signed char)(int)rintf(v[j].y / scale);
        q.z = (signed char)(int)rintf(v[j].z / scale);
        q.w = (signed char)(int)rintf(v[j].w / scale);
        o4[t + 256 * j] = q;
    }
}

// ---- int8 GEMM, 256x256 tile, 1024 threads / 16 waves, BK=128 dbuf ----
// Diagnosis across R2/R6/R9: every 512-thread 256^2 schedule lands at the same
// ~5860 cyc/CU/K-tile with no pipe saturated (LDS ~2050, MFMA ~310/SIMD) ->
// latency/sync-bound at 2 waves/SIMD. Fix: 16 waves (4x4 grid, 64x64 per
// wave) -> 4 waves/SIMD of latency hiding. Per-thread acc = 64 VGPR, total
// ~90-100 (R8 measured 88 for the same per-thread shape) -> fits the forced
// 128-VGPR cap without spills.
// Geometry: the ONLY empirically conflict-free fragment pattern (R1/R2/R6:
// 0 conflicts): 128 B rows, XOR swizzle lds[row][c]=global[row][c^((row&7)<<4)]
// baked into the pre-swizzled global source; 16x16x64 MFMA; ds_read_b128 at
// (row)*128 + (ks*64+kgrp)^sw.  Schedule: R2's counted-vmcnt double buffer --
// compute(buf); barrier; STAGE(buf,u+2); vmcnt(4) (never 0); barrier.
__global__ __launch_bounds__(1024) void gemm_i8_16w(const signed char* __restrict__ A,
                                                    const signed char* __restrict__ B,
                                                    const float* __restrict__ xs,
                                                    const float* __restrict__ wsc,
                                                    float* __restrict__ C) {
    constexpr int K = 4096;
    constexpr int N = 11008;
    constexpr int BK = 128;
    constexpr int NT = K / BK;       // 32
    constexpr int TILE = 256 * 128;  // 32 KB per matrix per buffer

    __shared__ __align__(16) signed char lsA[2][TILE];
    __shared__ __align__(16) signed char lsB[2][TILE];

    const int t = threadIdx.x;
    const int lane = t & 63;
    const int wid = t >> 6;    // 0..15
    const int wr = wid >> 2;   // 0..3 -> 64 output rows each
    const int wc = wid & 3;    // 0..3 -> 64 output cols each

    // XCD-aware swizzle: grid 1376 = 8 XCDs x 172 (bijective)
    const int wg = (blockIdx.x & 7) * ((int)gridDim.x >> 3) + ((int)blockIdx.x >> 3);
    const int by = wg / 43;
    const int bx = wg - by * 43;
    const int brow = by * 256;
    const int bcol = bx * 256;

    // staging: chunk = j*1024 + t; row = chunk>>3 (0..255), slot = t&7
    // 8 lanes x 16 B = 128 B contiguous global segments (R2's proven coalescing)
    const int srow = t >> 3;                              // 0..127 (+128 for j=1)
    const int scol = ((t & 7) * 16) ^ ((srow & 7) << 4);  // pre-swizzled source col
    const signed char* aSrc = A + (size_t)(brow + srow) * K + scol;
    const signed char* bSrc = B + (size_t)(bcol + srow) * K + scol;

    // fragment geometry (mfma_i32_16x16x64_i8): row = lane&15, k-grp = (lane>>4)*16
    const int arow0 = wr * 64 + (lane & 15);
    const int bcol0 = wc * 64 + (lane & 15);
    const int kgrp = (lane >> 4) * 16;
    const int sw = (lane & 7) << 4;  // row&7 == lane&7 for all fragment rows

    int4v acc[4][4];
#pragma unroll
    for (int m = 0; m < 4; ++m)
#pragma unroll
        for (int n = 0; n < 4; ++n) acc[m][n] = (int4v){0, 0, 0, 0};

#define STAGE(BUF, KT)                                                                      \
    do {                                                                                    \
        const size_t ko = (size_t)(KT)*BK;                                                  \
        _Pragma("unroll") for (int j = 0; j < 2; ++j)                                       \
            __builtin_amdgcn_global_load_lds(                                               \
                (glb_i8_t*)(aSrc + (size_t)(j * 128) * K + ko),                             \
                (lds_i8_t*)(&lsA[BUF][0] + (j * 1024 + t) * 16), 16, 0, 0);                 \
        _Pragma("unroll") for (int j = 0; j < 2; ++j)                                       \
            __builtin_amdgcn_global_load_lds(                                               \
                (glb_i8_t*)(bSrc + (size_t)(j * 128) * K + ko),                             \
                (lds_i8_t*)(&lsB[BUF][0] + (j * 1024 + t) * 16), 16, 0, 0);                 \
    } while (0)

    auto compute_tile = [&](const signed char* LA, const signed char* LB) {
#pragma unroll
        for (int ks = 0; ks < 2; ++ks) {
            const int col = (ks * 64 + kgrp) ^ sw;
            int4v bf[4], af[4];
#pragma unroll
            for (int n = 0; n < 4; ++n)
                bf[n] = *(const int4v*)(LB + (bcol0 + n * 16) * 128 + col);
#pragma unroll
            for (int mi = 0; mi < 4; ++mi)
                af[mi] = *(const int4v*)(LA + (arow0 + mi * 16) * 128 + col);
            __builtin_amdgcn_s_setprio(1);
#pragma unroll
            for (int mi = 0; mi < 4; ++mi)
#pragma unroll
                for (int n = 0; n < 4; ++n)
                    acc[mi][n] = __builtin_amdgcn_mfma_i32_16x16x64_i8(af[mi], bf[n],
                                                                       acc[mi][n], 0, 0, 0);
            __builtin_amdgcn_s_setprio(0);
        }
    };

    // prologue: stage tiles 0,1; wait for tile 0 only (tile 1 stays in flight)
    STAGE(0, 0);
    STAGE(1, 1);
    asm volatile("s_waitcnt vmcnt(4)" ::: "memory");
    __builtin_amdgcn_s_barrier();

#pragma unroll 1
    for (int u = 0; u < NT; ++u) {
        const int buf = u & 1;
        compute_tile(&lsA[buf][0], &lsB[buf][0]);
        __builtin_amdgcn_s_barrier();                     // all waves done reading buf
        STAGE(buf, (u + 2) & (NT - 1));                   // wrapped tail: redundant-but-safe
        asm volatile("s_waitcnt vmcnt(4)" ::: "memory");  // tile u+1 landed; u+2 in flight
        __builtin_amdgcn_s_barrier();
    }
#undef STAGE

    // drain staged loads before workgroup teardown
    asm volatile("s_waitcnt vmcnt(0)" ::: "memory");

    // epilogue: C/D frag layout col=lane&15, row=(lane>>4)*4+reg
    const int rgrp = (lane >> 4) * 4;
    float wsv[4];
#pragma unroll
    for (int n = 0; n < 4; ++n) wsv[n] = wsc[bcol + wc * 64 + n * 16 + (lane & 15)];
#pragma unroll
    for (int m = 0; m < 4; ++m) {
#pragma unroll
        for (int r = 0; r < 4; ++r) {
            const int row = brow + wr * 64 + m * 16 + rgrp + r;
            const float xsv = xs[row];
            const size_t base = (size_t)row * N + bcol + wc * 64 + (lane & 15);
#pragma unroll
            for (int n = 0; n < 4; ++n)
                C[base + n * 16] = (float)acc[m][n][r] * (xsv * wsv[n]);
        }
    }
}

extern "C" void kernel_launch(void* const* d_in, const int* in_sizes, int n_in,
                              void* d_out, int out_size, void* d_ws, size_t ws_size,
                              hipStream_t stream) {
    const float* x = (const float*)d_in[0];
    const float* w = (const float*)d_in[1];
    float* out = (float*)d_out;

    const int K = 4096;
    const int M = in_sizes[0] / K;   // 8192
    const int N = in_sizes[1] / K;   // 11008

    signed char* x8 = (signed char*)d_ws;
    signed char* w8 = x8 + (size_t)M * K;
    float* xscales = (float*)(w8 + (size_t)N * K);
    float* wscales = xscales + M;

    quant_rows_k<<<M, 256, 0, stream>>>(x, x8, xscales);
    quant_rows_k<<<N, 256, 0, stream>>>(w, w8, wscales);
    const int nwg = (M / 256) * (N / 256);   // 32*43 = 1376 = 8*172
    gemm_i8_16w<<<nwg, 1024, 0, stream>>>(x8, w8, xscales, wscales, out);
}